// Round 1
// baseline (37.766 us; speedup 1.0000x reference)
//
#include <hip/hip_runtime.h>

// Problem: B=8, N1=N2=2048, D=512, all float32.
// out[b,n,m] = dot(m1[b,n,:], w[:512]) + dot(m2[b,m,:], w[512:]) + bias[0]
// Memory-bound: 64 MiB in, 128 MiB out.

#define DDIM 512
#define BB   8
#define NN   2048
#define ROWS_PER_MAT (BB * NN)   // 16384

// One wave (64 lanes) per row. Each lane: 2 x float4 (8 floats), then
// wave-64 shfl reduction. Waves [0,16384) -> m1 with w1, [16384,32768) -> m2 with w2.
__global__ __launch_bounds__(256) void dot_kernel(const float* __restrict__ m1,
                                                  const float* __restrict__ m2,
                                                  const float* __restrict__ w,
                                                  float* __restrict__ s) {
    int wave = (int)((blockIdx.x * blockDim.x + threadIdx.x) >> 6);
    int lane = threadIdx.x & 63;

    const float* src;
    const float* wp;
    int row;
    if (wave < ROWS_PER_MAT) {
        src = m1; wp = w;        row = wave;
    } else {
        src = m2; wp = w + DDIM; row = wave - ROWS_PER_MAT;
    }

    const float4* rp = reinterpret_cast<const float4*>(src + (size_t)row * DDIM);
    const float4* wv = reinterpret_cast<const float4*>(wp);

    float4 a0 = rp[lane];
    float4 b0 = wv[lane];
    float4 a1 = rp[lane + 64];
    float4 b1 = wv[lane + 64];

    float acc = a0.x * b0.x + a0.y * b0.y + a0.z * b0.z + a0.w * b0.w
              + a1.x * b1.x + a1.y * b1.y + a1.z * b1.z + a1.w * b1.w;

    #pragma unroll
    for (int off = 32; off > 0; off >>= 1)
        acc += __shfl_down(acc, off, 64);

    if (lane == 0) s[wave] = acc;
}

// out[b,n,m] = s1[b,n] + s2[b,m] + bias. float4 stores, grid-stride.
__global__ __launch_bounds__(256) void add_kernel(const float* __restrict__ s1,
                                                  const float* __restrict__ s2,
                                                  const float* __restrict__ bias,
                                                  float4* __restrict__ out) {
    const size_t total4 = (size_t)BB * NN * (NN / 4);   // 8*2048*512 float4s
    const float bval = bias[0];
    const float4* s2v = reinterpret_cast<const float4*>(s2);

    for (size_t i = (size_t)blockIdx.x * blockDim.x + threadIdx.x;
         i < total4;
         i += (size_t)gridDim.x * blockDim.x) {
        int m4    = (int)(i & (NN / 4 - 1));        // 0..511
        size_t t  = i >> 9;                          // /512
        int n     = (int)(t & (NN - 1));             // 0..2047
        int b     = (int)(t >> 11);                  // 0..7

        float v1 = s1[b * NN + n] + bval;
        float4 v2 = s2v[b * (NN / 4) + m4];
        out[i] = make_float4(v2.x + v1, v2.y + v1, v2.z + v1, v2.w + v1);
    }
}

extern "C" void kernel_launch(void* const* d_in, const int* in_sizes, int n_in,
                              void* d_out, int out_size, void* d_ws, size_t ws_size,
                              hipStream_t stream) {
    const float* m1   = (const float*)d_in[0];
    const float* m2   = (const float*)d_in[1];
    const float* w    = (const float*)d_in[2];
    const float* bias = (const float*)d_in[3];
    float* out = (float*)d_out;

    float* s  = (float*)d_ws;          // s1: [0,16384), s2: [16384,32768)
    float* s1 = s;
    float* s2 = s + ROWS_PER_MAT;

    // 32768 rows total, 4 waves (rows) per 256-thread block -> 8192 blocks
    dot_kernel<<<(2 * ROWS_PER_MAT) / 4, 256, 0, stream>>>(m1, m2, w, s);

    // 8*2048*512 = 8.4M float4s; 2048 blocks x 256 threads, grid-stride (16 iters each)
    add_kernel<<<2048, 256, 0, stream>>>(s1, s2, bias, (float4*)out);
}